// Round 1
// baseline (330.217 us; speedup 1.0000x reference)
//
#include <hip/hip_runtime.h>

// ReActNet BasicBlock forward: out = BN(binary_conv3x3(sign(x), scale*sign(w))) + x
//
// i8 MFMA implicit-GEMM formulation:
//   sign(x) -> padded NHWC i8 tensor S[n][58][58][128]  (padding = 0, exact)
//   sign(w) -> A-fragment-layout i8 blob wfrag[otile][tap][ks][lane][16B]
//   dot[n,o,p] = sum over 9 taps x 4 k-slices of mfma_i32_32x32x32_i8
//   out = A[o]*dot + B[o] + x   (A = scale*inv, B = beta - mean*inv; dot exact i32)
// Zero padding contributes 0 in i8 => no border-pattern bias, no x==0 slow path.

#define N_   64
#define C_   128
#define H_   56
#define W_   56
#define HW_  (H_*W_)       // 3136
#define PH_  (H_+2)        // 58
#define PW_  (W_+2)        // 58
#define PHW_ (PH_*PW_)     // 3364
#define NPIX (N_*HW_)      // 200704

typedef int v4i  __attribute__((ext_vector_type(4)));
typedef int v16i __attribute__((ext_vector_type(16)));

// ---------------------------------------------------------------------------
// Kernel 1a: per-channel scale + BN fold. One wave per output channel.
//   AB[o] = {A, B} = {scale*inv, beta - mean*inv}
// ---------------------------------------------------------------------------
__global__ void prep_ab_kernel(const float* __restrict__ w,
                               const float* __restrict__ gamma,
                               const float* __restrict__ beta,
                               const float* __restrict__ bn_mean,
                               const float* __restrict__ bn_var,
                               float2* __restrict__ AB) {
    const int o = blockIdx.x;
    const int lane = threadIdx.x;          // 0..63
    const float* wo = w + o * 1152;

    float s = 0.f;
    #pragma unroll
    for (int k = 0; k < 18; k++) s += fabsf(wo[k * 64 + lane]);
    #pragma unroll
    for (int off = 32; off > 0; off >>= 1) s += __shfl_down(s, off);
    if (lane == 0) {
        float scale = s * (1.0f / 1152.0f);
        float inv = gamma[o] * rsqrtf(bn_var[o] + 1e-5f);
        float2 ab; ab.x = scale * inv; ab.y = beta[o] - bn_mean[o] * inv;
        AB[o] = ab;
    }
}

// ---------------------------------------------------------------------------
// Kernel 1b: weight signs in MFMA A-fragment layout.
//   A-frag (32x32x32 i8): lane l holds A[m = l&31][k = (l>>5)*16 + j], j=0..15
//   m = o within 32-tile, k = input channel within 32-slice.
//   wfrag[((otile*9 + tap)*4 + ks)*64 + lane] : v4i (16 bytes)
// ---------------------------------------------------------------------------
__global__ void prep_wfrag_kernel(const float* __restrict__ w,
                                  v4i* __restrict__ wfrag) {
    const int b = blockIdx.x;              // 0..35 = otile*9 + tap
    const int otile = b / 9, tap = b - 9 * otile;
    const int tid = threadIdx.x;
    const int ks = tid >> 6, lane = tid & 63;
    const int o = otile * 32 + (lane & 31);
    const int cbase = ks * 32 + (lane >> 5) * 16;
    const float* wp = w + o * 1152 + cbase * 9 + tap;   // w[o][c][tap], stride 9

    unsigned d[4];
    #pragma unroll
    for (int i = 0; i < 4; i++) {
        unsigned wd = 0;
        #pragma unroll
        for (int j = 0; j < 4; j++) {
            unsigned u = __float_as_uint(wp[(i * 4 + j) * 9]);
            unsigned byte = ((u << 1) == 0u) ? 0u : ((u >> 31) ? 0xFFu : 1u);
            wd |= byte << (8 * j);
        }
        d[i] = wd;
    }
    v4i t; t.x = (int)d[0]; t.y = (int)d[1]; t.z = (int)d[2]; t.w = (int)d[3];
    wfrag[((otile * 9 + tap) * 4 + ks) * 64 + lane] = t;
}

// ---------------------------------------------------------------------------
// Kernel 2: binarize x into padded NHWC i8.  256 thr = 64 pixels x 4 c-groups.
//   3136 blocks (8x the old pack parallelism -> out of the latency regime).
// ---------------------------------------------------------------------------
__global__ __launch_bounds__(256) void pack_s_kernel(
        const float* __restrict__ x, char* __restrict__ S) {
    const int tid = threadIdx.x;
    const int pixl = tid & 63, q = tid >> 6;      // q = channel quarter
    const int g = blockIdx.x * 64 + pixl;          // 0..NPIX-1
    const int n = g / HW_;
    const int p = g - n * HW_;
    const int row = p / W_, col = p - row * W_;

    const float* xp = x + ((size_t)n * C_ + q * 32) * HW_ + p;
    unsigned b[8];
    #pragma unroll
    for (int i = 0; i < 8; i++) {
        unsigned wd = 0;
        #pragma unroll
        for (int j = 0; j < 4; j++) {
            unsigned u = __float_as_uint(xp[(i * 4 + j) * HW_]);
            unsigned byte = ((u << 1) == 0u) ? 0u : ((u >> 31) ? 0xFFu : 1u);
            wd |= byte << (8 * j);
        }
        b[i] = wd;
    }
    char* dst = S + (size_t)((n * PH_ + row + 1) * PW_ + col + 1) * 128 + q * 32;
    v4i t0; t0.x=(int)b[0]; t0.y=(int)b[1]; t0.z=(int)b[2]; t0.w=(int)b[3];
    v4i t1; t1.x=(int)b[4]; t1.y=(int)b[5]; t1.z=(int)b[6]; t1.w=(int)b[7];
    ((v4i*)dst)[0] = t0;
    ((v4i*)dst)[1] = t1;
}

// ---------------------------------------------------------------------------
// Kernel 2b: zero the padded border pixels (128 B each).
// ---------------------------------------------------------------------------
__global__ void border_s_kernel(char* __restrict__ S) {
    int bt = blockIdx.x * 256 + threadIdx.x;
    if (bt >= N_ * 228) return;                 // 2*58 + 2*56 = 228 per image
    int n = bt / 228, e = bt - n * 228;
    int ph, pw;
    if (e < 58)       { ph = 0;  pw = e; }
    else if (e < 116) { ph = 57; pw = e - 58; }
    else { int i = e - 116; ph = 1 + (i >> 1); pw = (i & 1) ? 57 : 0; }
    v4i z = {};
    v4i* dst = (v4i*)(S + (size_t)((n * PH_ + ph) * PW_ + pw) * 128);
    #pragma unroll
    for (int i = 0; i < 8; i++) dst[i] = z;
}

// ---------------------------------------------------------------------------
// Kernel 3: i8 MFMA conv + BN + residual.
//   GEMM: M = out-channels, N = pixels, K = 128 c x 9 taps.
//   Block (256 thr, 4 waves): 64 o x 128 pixels. Wave: 32 o x 2x32 pixels.
//   3136 blocks, XCD-bijective swizzle (3136 % 8 == 0).
//   Weights: global A-frag loads (L2-resident, 147 KB total). No LDS/barriers.
//   C/D layout (verified, dtype-indep): col = lane&31 (pixel),
//     row = (reg&3) + 8*(reg>>2) + 4*(lane>>5)  (o within 32-tile).
// ---------------------------------------------------------------------------
__global__ __launch_bounds__(256, 4) void bconv_mfma_kernel(
        const char* __restrict__ S,
        const v4i* __restrict__ wfrag,
        const float2* __restrict__ AB,
        const float* __restrict__ x,
        float* __restrict__ out) {
    const int tid = threadIdx.x;
    const int lane = tid & 63;
    const int wid = tid >> 6;                  // 0..3
    // XCD swizzle: consecutive work ids stay on one XCD's L2.
    const int b0 = blockIdx.x;
    const int bid = (b0 & 7) * 392 + (b0 >> 3);
    const int pb = bid >> 1;                   // pixel-block 0..1567 (128 pix)
    const int oh = bid & 1;                    // o-half
    const int wo = wid & 1, wp = wid >> 1;
    const int otile = oh * 2 + wo;             // 0..3
    const int l31 = lane & 31, lhi = lane >> 5;

    // Per-lane pixel geometry for the wave's two 32-pixel tiles.
    int n0, p0, n1, p1; int sb0, sb1;
    {
        int g = (pb * 4 + wp * 2) * 32 + l31;
        n0 = g / HW_; p0 = g - n0 * HW_;
        int r = p0 / W_, c = p0 - r * W_;
        sb0 = ((n0 * PH_ + r + 1) * PW_ + c + 1) * 128 + lhi * 16;
    }
    {
        int g = (pb * 4 + wp * 2 + 1) * 32 + l31;
        n1 = g / HW_; p1 = g - n1 * HW_;
        int r = p1 / W_, c = p1 - r * W_;
        sb1 = ((n1 * PH_ + r + 1) * PW_ + c + 1) * 128 + lhi * 16;
    }

    const v4i* wf = wfrag + otile * (9 * 4 * 64) + lane;

    v16i acc0 = {};
    v16i acc1 = {};

    #pragma unroll
    for (int t = 0; t < 9; t++) {
        const int dh = t / 3, dw = t - 3 * dh;
        const int toff = ((dh - 1) * PW_ + (dw - 1)) * 128;
        const char* sa0 = S + (sb0 + toff);
        const char* sa1 = S + (sb1 + toff);
        const v4i* wt = wf + t * 256;
        #pragma unroll
        for (int ks = 0; ks < 4; ks++) {
            v4i a  = wt[ks * 64];
            v4i bb0 = *(const v4i*)(sa0 + ks * 32);
            v4i bb1 = *(const v4i*)(sa1 + ks * 32);
            acc0 = __builtin_amdgcn_mfma_i32_32x32x32_i8(a, bb0, acc0, 0, 0, 0);
            acc1 = __builtin_amdgcn_mfma_i32_32x32x32_i8(a, bb1, acc1, 0, 0, 0);
        }
    }

    // Epilogue: out = A*dot + B + x
    const int orow = otile * 32 + 4 * lhi;
    {
        unsigned base = (unsigned)n0 * (unsigned)(C_ * HW_) + (unsigned)p0;
        #pragma unroll
        for (int r = 0; r < 16; r++) {
            int o = orow + (r & 3) + 8 * (r >> 2);
            float2 ab = AB[o];
            unsigned idx = base + (unsigned)o * (unsigned)HW_;
            out[idx] = fmaf(ab.x, (float)acc0[r], ab.y) + x[idx];
        }
    }
    {
        unsigned base = (unsigned)n1 * (unsigned)(C_ * HW_) + (unsigned)p1;
        #pragma unroll
        for (int r = 0; r < 16; r++) {
            int o = orow + (r & 3) + 8 * (r >> 2);
            float2 ab = AB[o];
            unsigned idx = base + (unsigned)o * (unsigned)HW_;
            out[idx] = fmaf(ab.x, (float)acc1[r], ab.y) + x[idx];
        }
    }
}

// ---------------------------------------------------------------------------
extern "C" void kernel_launch(void* const* d_in, const int* in_sizes, int n_in,
                              void* d_out, int out_size, void* d_ws, size_t ws_size,
                              hipStream_t stream) {
    const float* x      = (const float*)d_in[0];
    const float* weight = (const float*)d_in[1];
    const float* gamma  = (const float*)d_in[2];
    const float* beta   = (const float*)d_in[3];
    const float* bnmean = (const float*)d_in[4];
    const float* bnvar  = (const float*)d_in[5];
    float* out = (float*)d_out;

    char* ws = (char*)d_ws;
    v4i*    wfrag = (v4i*)ws;                       // 147456 B
    float2* AB    = (float2*)(ws + 147456);         // 1024 B
    char*   S     = ws + 148480;                    // 64*3364*128 = 27541504 B

    prep_ab_kernel<<<128, 64, 0, stream>>>(weight, gamma, beta, bnmean, bnvar, AB);
    prep_wfrag_kernel<<<36, 256, 0, stream>>>(weight, wfrag);
    pack_s_kernel<<<NPIX / 64, 256, 0, stream>>>(x, S);
    border_s_kernel<<<(N_ * 228 + 255) / 256, 256, 0, stream>>>(S);
    bconv_mfma_kernel<<<NPIX / 64, 256, 0, stream>>>(S, wfrag, AB, x, out);
}